// Round 9
// baseline (7289.475 us; speedup 1.0000x reference)
//
#include <hip/hip_runtime.h>

// 2-layer bidirectional GRU (T=512,B=32,I=H=O=512) + FC, bf16 MFMA compute.
//
// Round 9: r8 shell (XCD election, L2 atomic counters, wave0 poll + LDS go,
// barrier#2 + per-WG publish) with the step body restructured:
//  - h_prev loaded DIRECTLY to VGPRs (32x b128 per wave) from y in XCD L2;
//    no gl_lds, no LDS staging, no barrier#1, no bank conflicts.
//  - VMEM ordering: poll happens with ZERO outstanding VMEM (its vmcnt(0)
//    no longer drains gi HBM prefetches); gi+h loads issue after the poll;
//    compiler inserts counted waits before MFMA/epilogue uses.
//  - Per-wave j-slice j0=role*32+p*16; W_hh (192 VGPR) persistent; h in f32.

typedef unsigned short u16;
typedef __attribute__((ext_vector_type(8))) short bf16x8;
typedef __attribute__((ext_vector_type(4))) float f32x4;

__device__ __forceinline__ u16 f2bf(float f) {
  unsigned u = __float_as_uint(f);
  u += 0x7fffu + ((u >> 16) & 1u);
  return (u16)(u >> 16);
}
__device__ __forceinline__ float bf2f(unsigned v) {   // low 16 bits = bf16
  return __uint_as_float(v << 16);
}

template<int AUX>
__device__ __forceinline__ void gl_lds16(const void* g, void* l) {
  __builtin_amdgcn_global_load_lds((const __attribute__((address_space(1))) void*)g,
                                   (__attribute__((address_space(3))) void*)l, 16, 0, AUX);
}

__device__ __forceinline__ void st_u64_sc0(void* p, uint2 v) {
  asm volatile("global_store_dwordx2 %0, %1, off sc0" :: "v"(p), "v"(v) : "memory");
}
// L2-executed atomic read (never L1-stale). Call only with no other VMEM
// outstanding: the vmcnt(0) then waits just this atomic.
__device__ __forceinline__ unsigned atom_rd_l2(unsigned* p) {
  unsigned r;
  asm volatile("global_atomic_add %0, %1, %2, off sc0\n\ts_waitcnt vmcnt(0)"
               : "=v"(r) : "v"(p), "v"(0u) : "memory");
  return r;
}
__device__ __forceinline__ void atom_add_l2(unsigned* p, unsigned v) {
  asm volatile("global_atomic_add %0, %1, off" :: "v"(p), "v"(v) : "memory");
}

// ---------------- utility kernels ----------------

__global__ void k_zero(unsigned* p, int n) {
  int i = blockIdx.x * blockDim.x + threadIdx.x;
  if (i < n) p[i] = 0u;
}

__global__ void k_cvt(const float* __restrict__ s, u16* __restrict__ d, int n) {
  int i = (blockIdx.x * blockDim.x + threadIdx.x) * 4;
  if (i < n) {
    float4 v = *(const float4*)(s + i);
    unsigned a = (unsigned)f2bf(v.x) | ((unsigned)f2bf(v.y) << 16);
    unsigned b = (unsigned)f2bf(v.z) | ((unsigned)f2bf(v.w) << 16);
    uint2 o; o.x = a; o.y = b;
    *(uint2*)(d + i) = o;
  }
}

__global__ void k_copyf(const float* __restrict__ s, float* __restrict__ d, int n) {
  int i = blockIdx.x * blockDim.x + threadIdx.x;
  if (i < n) d[i] = s[i];
}

// ------- tiled bf16 MFMA GEMM:  C[M,N] = A[M,K] * B[N,K]^T + bias -------

template<bool BF16OUT>
__global__ __launch_bounds__(256) void k_gemm(
    const u16* __restrict__ A, const u16* __restrict__ B,
    const float* __restrict__ bias, void* __restrict__ Cv,
    int N, int K)
{
  __shared__ u16 As[128 * 32];
  __shared__ u16 Bs[128 * 32];
  const int tid = threadIdx.x;
  const int w = tid >> 6, l = tid & 63;
  const int bm = blockIdx.x, bn = blockIdx.y;
  const int lj = l & 15, lk = l >> 4;
  const int wm = (w & 1) * 64, wn = (w >> 1) * 64;
  const int srow = l >> 2, scol = (l & 3) * 8;
  f32x4 acc[4][4] = {};
  const u16* Ab = A + (size_t)bm * 128 * K;
  const u16* Bb = B + (size_t)bn * 128 * K;

  for (int kt = 0; kt < K; kt += 32) {
#pragma unroll
    for (int i = 0; i < 2; ++i) {
      int r0 = i * 64 + w * 16;
      gl_lds16<0>(Ab + (size_t)(r0 + srow) * K + kt + scol, &As[r0 * 32]);
      gl_lds16<0>(Bb + (size_t)(r0 + srow) * K + kt + scol, &Bs[r0 * 32]);
    }
    __syncthreads();
    bf16x8 af[4], bf[4];
#pragma unroll
    for (int i = 0; i < 4; ++i) af[i] = *(const bf16x8*)&As[(wm + i * 16 + lj) * 32 + lk * 8];
#pragma unroll
    for (int j = 0; j < 4; ++j) bf[j] = *(const bf16x8*)&Bs[(wn + j * 16 + lj) * 32 + lk * 8];
#pragma unroll
    for (int i = 0; i < 4; ++i)
#pragma unroll
      for (int j = 0; j < 4; ++j)
        acc[i][j] = __builtin_amdgcn_mfma_f32_16x16x32_bf16(af[i], bf[j], acc[i][j], 0, 0, 0);
    __syncthreads();
  }

#pragma unroll
  for (int i = 0; i < 4; ++i)
#pragma unroll
    for (int j = 0; j < 4; ++j) {
      int col = bn * 128 + wn + j * 16 + lj;
      float bv = bias[col];
#pragma unroll
      for (int r2 = 0; r2 < 4; ++r2) {
        int row = bm * 128 + wm + i * 16 + lk * 4 + r2;
        float v = acc[i][j][r2] + bv;
        if (BF16OUT) ((u16*)Cv)[(size_t)row * N + col] = f2bf(v);
        else         ((float*)Cv)[(size_t)row * N + col] = v;
      }
    }
}

// ---------------- persistent GRU layer (both directions) ----------------

__global__ __launch_bounds__(256, 1) void k_gru(
    const u16*  __restrict__ gi,      // [512*32][3072] bf16; fwd 0:1536, bwd 1536:3072
    const float* __restrict__ whhf,   // [1536][512]
    const float* __restrict__ whhb,
    const float* __restrict__ bhhf,   // [1536]
    const float* __restrict__ bhhb,
    const float* __restrict__ h0,     // this layer: [2][32][512] f32
    const u16*  __restrict__ hinit,   // this layer: [2][32][512] bf16
    u16* __restrict__ y,              // [512][32][1024] bf16 (exchange + next layer)
    float* __restrict__ hn,           // this layer: [2][32][512] f32 (d_out)
    unsigned* __restrict__ cnt,       // this layer: 4 words, 128-B apart (idx q*32)
    unsigned* __restrict__ elect)     // this layer: [0..7] tickets, [8] winner
{
  __shared__ int sh_role;
  __shared__ int sh_go;
  const int tid = threadIdx.x;

  // ---- XCD election (AGENT/LLC atomics; one-time) ----
  if (tid == 0) {
    sh_go = -1;
    unsigned xcc;
    asm volatile("s_getreg_b32 %0, hwreg(HW_REG_XCC_ID)" : "=s"(xcc));
    xcc &= 7u;
    unsigned t = __hip_atomic_fetch_add(&elect[xcc], 1u, __ATOMIC_RELAXED,
                                        __HIP_MEMORY_SCOPE_AGENT);
    int role = -1;
    if (t < 16u) {
      if (t == 15u) {
        unsigned expected = 0u;
        __hip_atomic_compare_exchange_strong(&elect[8], &expected, xcc + 1u,
            __ATOMIC_RELAXED, __ATOMIC_RELAXED, __HIP_MEMORY_SCOPE_AGENT);
      }
      unsigned cap = 0;
      for (;;) {
        unsigned wv = __hip_atomic_load(&elect[8], __ATOMIC_RELAXED,
                                        __HIP_MEMORY_SCOPE_AGENT);
        if (wv != 0u) { if (wv == xcc + 1u) role = (int)t; break; }
        if (++cap > (1u << 22)) break;
        __builtin_amdgcn_s_sleep(2);
      }
    }
    sh_role = role;
  }
  __syncthreads();
  const int role = sh_role;
  if (role < 0) return;               // whole WG exits together

  const int w = tid >> 6, l = tid & 63;
  const int dir = w >> 1, p = w & 1;
  const int j0 = role * 32 + p * 16;
  const int lj = l & 15, lk = l >> 4;
  const float* whh = dir ? whhb : whhf;
  const float* bhh = dir ? bhhb : bhhf;
  volatile int* go_v = (volatile int*)&sh_go;

  // persistent W_hh fragments (A-operand)
  bf16x8 bfr[3][16];
#pragma unroll
  for (int g = 0; g < 3; ++g) {
    const float* wr = whh + (size_t)(g * 512 + j0 + lj) * 512;
#pragma unroll
    for (int kc = 0; kc < 16; ++kc) {
      const float* s4 = wr + kc * 32 + lk * 8;
      float4 a = *(const float4*)s4;
      float4 b = *(const float4*)(s4 + 4);
      bf16x8 v;
      v[0] = (short)f2bf(a.x); v[1] = (short)f2bf(a.y); v[2] = (short)f2bf(a.z); v[3] = (short)f2bf(a.w);
      v[4] = (short)f2bf(b.x); v[5] = (short)f2bf(b.y); v[6] = (short)f2bf(b.z); v[7] = (short)f2bf(b.w);
      bfr[g][kc] = v;
    }
  }
  f32x4 bbv[3];
#pragma unroll
  for (int g = 0; g < 3; ++g)
    bbv[g] = *(const f32x4*)&bhh[g * 512 + j0 + lk * 4];

  float hreg[2][4];
#pragma unroll
  for (int bt = 0; bt < 2; ++bt) {
    f32x4 hv = *(const f32x4*)&h0[((size_t)dir * 32 + bt * 16 + lj) * 512 + j0 + lk * 4];
#pragma unroll
    for (int r = 0; r < 4; ++r) hreg[bt][r] = hv[r];
  }

  for (int s = 0; s < 512; ++s) {
    const int tq = dir ? (511 - s) : s;

    // ---- wait: all 16 WGs finished step s-1 (no VMEM outstanding here) ----
    if (s > 0) {
      if (w == 0) {
        const unsigned target = 4u * (unsigned)s;
        unsigned cap = 0;
        for (;;) {
          unsigned v = 0xFFFFFFFFu;
          if (l < 4) v = atom_rd_l2(cnt + (l << 5));
          if (__all((int)((l < 4) ? (v >= target) : 1))) break;
          if (++cap > (1u << 14)) break;   // terminates, never hangs
        }
        if (l == 0) *go_v = s;             // LDS broadcast to waves 1..3
      } else {
        unsigned cap = 0;
        while (*go_v < s) { if (++cap > (1u << 20)) break; }
      }
    }
    asm volatile("" ::: "memory");         // no load hoisting above the wait

    // gi loads for THIS step (6x 8-B); consumed in epilogue (~800cy later)
    uint2 gu[2][3];
#pragma unroll
    for (int bt = 0; bt < 2; ++bt)
#pragma unroll
      for (int g = 0; g < 3; ++g)
        gu[bt][g] = *(const uint2*)(gi + ((size_t)tq * 32 + bt * 16 + lj) * 3072
                                    + dir * 1536 + g * 512 + j0 + lk * 4);

    // h_prev direct to VGPR: lane (lj,lk) reads rows b=lj and b=16+lj,
    // cols kc*32+lk*8 (byte-identical to the old LDS path)
    bf16x8 ha[16], hb[16];
    {
      const u16* src; int rstride, cbase;
      if (s == 0) { src = hinit + (size_t)dir * 32 * 512; rstride = 512; cbase = 0; }
      else { int tp = dir ? (tq + 1) : (tq - 1); src = y + (size_t)tp * 32 * 1024; rstride = 1024; cbase = dir * 512; }
      const u16* b0 = src + (size_t)lj * rstride + cbase + lk * 8;
      const u16* b1 = src + (size_t)(16 + lj) * rstride + cbase + lk * 8;
#pragma unroll
      for (int kc = 0; kc < 16; ++kc) {
        ha[kc] = *(const bf16x8*)(b0 + kc * 32);
        hb[kc] = *(const bf16x8*)(b1 + kc * 32);
      }
    }

    f32x4 acc[2][3];
#pragma unroll
    for (int bt = 0; bt < 2; ++bt)
#pragma unroll
      for (int g = 0; g < 3; ++g)
        acc[bt][g] = bbv[g];

#pragma unroll
    for (int kc = 0; kc < 16; ++kc) {
#pragma unroll
      for (int g = 0; g < 3; ++g) {        // swapped operands: D[row=j][col=b]
        acc[0][g] = __builtin_amdgcn_mfma_f32_16x16x32_bf16(bfr[g][kc], ha[kc], acc[0][g], 0, 0, 0);
        acc[1][g] = __builtin_amdgcn_mfma_f32_16x16x32_bf16(bfr[g][kc], hb[kc], acc[1][g], 0, 0, 0);
      }
    }

    // epilogue: gates + h update; one 8-B sc0 store per (lane, bt)
#pragma unroll
    for (int bt = 0; bt < 2; ++bt) {
      const int b = bt * 16 + lj;
      unsigned q[4];
      float hv[4];
#pragma unroll
      for (int r = 0; r < 4; ++r) {
        unsigned w0 = (r & 1) ? (((const unsigned*)&gu[bt][0])[r >> 1] >> 16)
                              : (((const unsigned*)&gu[bt][0])[r >> 1] & 0xffffu);
        unsigned w1 = (r & 1) ? (((const unsigned*)&gu[bt][1])[r >> 1] >> 16)
                              : (((const unsigned*)&gu[bt][1])[r >> 1] & 0xffffu);
        unsigned w2 = (r & 1) ? (((const unsigned*)&gu[bt][2])[r >> 1] >> 16)
                              : (((const unsigned*)&gu[bt][2])[r >> 1] & 0xffffu);
        float rr = 1.f / (1.f + __expf(-(bf2f(w0) + acc[bt][0][r])));
        float zz = 1.f / (1.f + __expf(-(bf2f(w1) + acc[bt][1][r])));
        float nx = bf2f(w2) + rr * acc[bt][2][r];
        float nn = 1.f - 2.f / (1.f + __expf(2.f * nx));
        float h = (1.f - zz) * nn + zz * hreg[bt][r];
        hreg[bt][r] = h;
        hv[r] = h;
        q[r] = (unsigned)f2bf(h);
      }
      uint2 pack; pack.x = q[0] | (q[1] << 16); pack.y = q[2] | (q[3] << 16);
      st_u64_sc0(y + ((size_t)tq * 32 + b) * 1024 + dir * 512 + j0 + lk * 4, pack);
      if (s == 511) {
        float4 o; o.x = hv[0]; o.y = hv[1]; o.z = hv[2]; o.w = hv[3];
        *(float4*)&hn[((size_t)dir * 32 + b) * 512 + j0 + lk * 4] = o;
      }
    }

    asm volatile("s_waitcnt vmcnt(0)" ::: "memory");  // only the 2 y-stores left
    __syncthreads();                      // all 4 waves drained (barrier#2)
    if (tid == 0) atom_add_l2(cnt + ((role & 3) << 5), 1u);  // publish at L2
  }
}

// ---------------- host ----------------

extern "C" void kernel_launch(void* const* d_in, const int* in_sizes, int n_in,
                              void* d_out, int out_size, void* d_ws, size_t ws_size,
                              hipStream_t stream)
{
  const float* x     = (const float*)d_in[0];
  const float* h     = (const float*)d_in[1];
  const float* wih0f = (const float*)d_in[2];
  const float* whh0f = (const float*)d_in[3];
  const float* bih0f = (const float*)d_in[4];
  const float* bhh0f = (const float*)d_in[5];
  const float* wih0b = (const float*)d_in[6];
  const float* whh0b = (const float*)d_in[7];
  const float* bih0b = (const float*)d_in[8];
  const float* bhh0b = (const float*)d_in[9];
  const float* wih1f = (const float*)d_in[10];
  const float* whh1f = (const float*)d_in[11];
  const float* bih1f = (const float*)d_in[12];
  const float* bhh1f = (const float*)d_in[13];
  const float* wih1b = (const float*)d_in[14];
  const float* whh1b = (const float*)d_in[15];
  const float* bih1b = (const float*)d_in[16];
  const float* bhh1b = (const float*)d_in[17];
  const float* fcw   = (const float*)d_in[18];
  const float* fcb   = (const float*)d_in[19];
  (void)in_sizes; (void)n_in; (void)out_size;

  char* ws = (char*)d_ws;
  size_t off = 0;
  auto alloc = [&](size_t bytes) { void* p = ws + off; off += (bytes + 255) & ~(size_t)255; return p; };
  u16*      gi    = (u16*)     alloc(16384ull * 3072 * 2);   // 100.7 MB
  u16*      y0    = (u16*)     alloc(16384ull * 1024 * 2);   // 33.6 MB
  char*     y1r   = (char*)    alloc(16384ull * 1024 * 2);   // 33.6 MB (aliased below)
  u16*      Wfc   = (u16*)     alloc(512ull * 1024 * 2);
  u16*      hinit = (u16*)     alloc(4ull * 32 * 512 * 2);
  float*    bias0 = (float*)   alloc(3072 * 4);
  float*    bias1 = (float*)   alloc(3072 * 4);
  unsigned* sync  = (unsigned*)alloc(512 * 4);
  // layout (u32 idx): [0..127] cnt L0 (quads at 0/32/64/96); [128..255] cnt L1;
  //                   [256..264] elect L0; [384..392] elect L1
  size_t need = off;

  if (ws_size < need) {  // diagnosable failure instead of a page fault
    hipMemsetAsync(d_out, 0, (size_t)out_size * sizeof(float), stream);
    return;
  }

  // xb / Wih0 / Wih1 die after GEMM1; y1 written only after that -> alias.
  u16* y1   = (u16*)y1r;
  u16* xb   = (u16*)y1r;
  u16* Wih0 = (u16*)(y1r + 16777216);
  u16* Wih1 = (u16*)(y1r + 16777216 + 3145728);

  float* out = (float*)d_out;
  float* hn  = out + 512ull * 32 * 512;

  k_zero<<<2, 256, 0, stream>>>(sync, 512);
  auto cvt = [&](const float* s, u16* d, int n) {
    k_cvt<<<dim3((n / 4 + 255) / 256), 256, 0, stream>>>(s, d, n);
  };
  cvt(x, xb, 16384 * 512);
  cvt(wih0f, Wih0, 1536 * 512);
  cvt(wih0b, Wih0 + 1536 * 512, 1536 * 512);
  cvt(wih1f, Wih1, 1536 * 1024);
  cvt(wih1b, Wih1 + 1536 * 1024, 1536 * 1024);
  cvt(fcw, Wfc, 512 * 1024);
  cvt(h, hinit, 4 * 32 * 512);
  k_copyf<<<6, 256, 0, stream>>>(bih0f, bias0, 1536);
  k_copyf<<<6, 256, 0, stream>>>(bih0b, bias0 + 1536, 1536);
  k_copyf<<<6, 256, 0, stream>>>(bih1f, bias1, 1536);
  k_copyf<<<6, 256, 0, stream>>>(bih1b, bias1 + 1536, 1536);

  // layer 0
  k_gemm<true><<<dim3(128, 24), 256, 0, stream>>>(xb, Wih0, bias0, gi, 3072, 512);
  k_gru<<<128, 256, 0, stream>>>(gi, whh0f, whh0b, bhh0f, bhh0b,
                                 h, hinit, y0, hn, sync, sync + 256);
  // layer 1
  k_gemm<true><<<dim3(128, 24), 256, 0, stream>>>(y0, Wih1, bias1, gi, 3072, 1024);
  k_gru<<<128, 256, 0, stream>>>(gi, whh1f, whh1b, bhh1f, bhh1b,
                                 h + 2 * 32 * 512, hinit + 2 * 32 * 512,
                                 y1, hn + 2ull * 32 * 512, sync + 128, sync + 384);
  // FC
  k_gemm<false><<<dim3(128, 4), 256, 0, stream>>>(y1, Wfc, fcb, out, 512, 1024);
}

// Round 10
// 3858.037 us; speedup vs baseline: 1.8894x; 1.8894x over previous
//
#include <hip/hip_runtime.h>

// 2-layer bidirectional GRU (T=512,B=32,I=H=O=512) + FC, bf16 MFMA compute.
//
// Round 10 = r8 (best: XCD election, L2 atomic counters, gl_lds staging,
// 2 barriers, per-WG publish) + two serial-chain fixes:
//  (1) gi double-buffer prefetch: next step's 6 gi loads issue right after
//      the staging barrier (covered by MFMA+epilogue), so the poll's
//      vmcnt(0) no longer drains ~900cy of HBM latency every step.
//  (2) v_rcp_f32 sigmoid/tanh: kills 24 precise-divide sequences per lane
//      per step (~10 instr each) in the epilogue.
// Everything else byte-identical to r8.

typedef unsigned short u16;
typedef __attribute__((ext_vector_type(8))) short bf16x8;
typedef __attribute__((ext_vector_type(4))) float f32x4;

__device__ __forceinline__ u16 f2bf(float f) {
  unsigned u = __float_as_uint(f);
  u += 0x7fffu + ((u >> 16) & 1u);
  return (u16)(u >> 16);
}
__device__ __forceinline__ float bf2f(unsigned v) {   // low 16 bits = bf16
  return __uint_as_float(v << 16);
}
__device__ __forceinline__ float frcp(float x) {      // v_rcp_f32, ~1ulp
  float r;
  asm("v_rcp_f32 %0, %1" : "=v"(r) : "v"(x));
  return r;
}

template<int AUX>
__device__ __forceinline__ void gl_lds16(const void* g, void* l) {
  __builtin_amdgcn_global_load_lds((const __attribute__((address_space(1))) void*)g,
                                   (__attribute__((address_space(3))) void*)l, 16, 0, AUX);
}

__device__ __forceinline__ void st_u64_sc0(void* p, uint2 v) {
  asm volatile("global_store_dwordx2 %0, %1, off sc0" :: "v"(p), "v"(v) : "memory");
}
// L2-executed atomic read (never L1-stale). Call only with no other VMEM
// outstanding: the vmcnt(0) then waits just this atomic.
__device__ __forceinline__ unsigned atom_rd_l2(unsigned* p) {
  unsigned r;
  asm volatile("global_atomic_add %0, %1, %2, off sc0\n\ts_waitcnt vmcnt(0)"
               : "=v"(r) : "v"(p), "v"(0u) : "memory");
  return r;
}
__device__ __forceinline__ void atom_add_l2(unsigned* p, unsigned v) {
  asm volatile("global_atomic_add %0, %1, off" :: "v"(p), "v"(v) : "memory");
}

// ---------------- utility kernels ----------------

__global__ void k_zero(unsigned* p, int n) {
  int i = blockIdx.x * blockDim.x + threadIdx.x;
  if (i < n) p[i] = 0u;
}

__global__ void k_cvt(const float* __restrict__ s, u16* __restrict__ d, int n) {
  int i = (blockIdx.x * blockDim.x + threadIdx.x) * 4;
  if (i < n) {
    float4 v = *(const float4*)(s + i);
    unsigned a = (unsigned)f2bf(v.x) | ((unsigned)f2bf(v.y) << 16);
    unsigned b = (unsigned)f2bf(v.z) | ((unsigned)f2bf(v.w) << 16);
    uint2 o; o.x = a; o.y = b;
    *(uint2*)(d + i) = o;
  }
}

__global__ void k_copyf(const float* __restrict__ s, float* __restrict__ d, int n) {
  int i = blockIdx.x * blockDim.x + threadIdx.x;
  if (i < n) d[i] = s[i];
}

// ------- tiled bf16 MFMA GEMM:  C[M,N] = A[M,K] * B[N,K]^T + bias -------

template<bool BF16OUT>
__global__ __launch_bounds__(256) void k_gemm(
    const u16* __restrict__ A, const u16* __restrict__ B,
    const float* __restrict__ bias, void* __restrict__ Cv,
    int N, int K)
{
  __shared__ u16 As[128 * 32];
  __shared__ u16 Bs[128 * 32];
  const int tid = threadIdx.x;
  const int w = tid >> 6, l = tid & 63;
  const int bm = blockIdx.x, bn = blockIdx.y;
  const int lj = l & 15, lk = l >> 4;
  const int wm = (w & 1) * 64, wn = (w >> 1) * 64;
  const int srow = l >> 2, scol = (l & 3) * 8;
  f32x4 acc[4][4] = {};
  const u16* Ab = A + (size_t)bm * 128 * K;
  const u16* Bb = B + (size_t)bn * 128 * K;

  for (int kt = 0; kt < K; kt += 32) {
#pragma unroll
    for (int i = 0; i < 2; ++i) {
      int r0 = i * 64 + w * 16;
      gl_lds16<0>(Ab + (size_t)(r0 + srow) * K + kt + scol, &As[r0 * 32]);
      gl_lds16<0>(Bb + (size_t)(r0 + srow) * K + kt + scol, &Bs[r0 * 32]);
    }
    __syncthreads();
    bf16x8 af[4], bf[4];
#pragma unroll
    for (int i = 0; i < 4; ++i) af[i] = *(const bf16x8*)&As[(wm + i * 16 + lj) * 32 + lk * 8];
#pragma unroll
    for (int j = 0; j < 4; ++j) bf[j] = *(const bf16x8*)&Bs[(wn + j * 16 + lj) * 32 + lk * 8];
#pragma unroll
    for (int i = 0; i < 4; ++i)
#pragma unroll
      for (int j = 0; j < 4; ++j)
        acc[i][j] = __builtin_amdgcn_mfma_f32_16x16x32_bf16(af[i], bf[j], acc[i][j], 0, 0, 0);
    __syncthreads();
  }

#pragma unroll
  for (int i = 0; i < 4; ++i)
#pragma unroll
    for (int j = 0; j < 4; ++j) {
      int col = bn * 128 + wn + j * 16 + lj;
      float bv = bias[col];
#pragma unroll
      for (int r2 = 0; r2 < 4; ++r2) {
        int row = bm * 128 + wm + i * 16 + lk * 4 + r2;
        float v = acc[i][j][r2] + bv;
        if (BF16OUT) ((u16*)Cv)[(size_t)row * N + col] = f2bf(v);
        else         ((float*)Cv)[(size_t)row * N + col] = v;
      }
    }
}

// ---------------- persistent GRU layer (both directions) ----------------

#define LSTR 536  // padded LDS row stride in bf16 elems (1072 B, 16B-aligned)

__global__ __launch_bounds__(256, 1) void k_gru(
    const u16*  __restrict__ gi,      // [512*32][3072] bf16; fwd 0:1536, bwd 1536:3072
    const float* __restrict__ whhf,   // [1536][512]
    const float* __restrict__ whhb,
    const float* __restrict__ bhhf,   // [1536]
    const float* __restrict__ bhhb,
    const float* __restrict__ h0,     // this layer: [2][32][512] f32
    const u16*  __restrict__ hinit,   // this layer: [2][32][512] bf16
    u16* __restrict__ y,              // [512][32][1024] bf16 (exchange + next layer)
    float* __restrict__ hn,           // this layer: [2][32][512] f32 (d_out)
    unsigned* __restrict__ cnt,       // this layer: 4 words, 128-B apart (idx q*32)
    unsigned* __restrict__ elect)     // this layer: [0..7] tickets, [8] winner
{
  __shared__ u16 hl[2][32 * LSTR];    // 68.6 KB
  __shared__ int sh_role;
  __shared__ int sh_go;
  const int tid = threadIdx.x;

  // ---- XCD election (AGENT/LLC atomics; one-time) ----
  if (tid == 0) {
    sh_go = -1;
    unsigned xcc;
    asm volatile("s_getreg_b32 %0, hwreg(HW_REG_XCC_ID)" : "=s"(xcc));
    xcc &= 7u;
    unsigned t = __hip_atomic_fetch_add(&elect[xcc], 1u, __ATOMIC_RELAXED,
                                        __HIP_MEMORY_SCOPE_AGENT);
    int role = -1;
    if (t < 16u) {
      if (t == 15u) {
        unsigned expected = 0u;
        __hip_atomic_compare_exchange_strong(&elect[8], &expected, xcc + 1u,
            __ATOMIC_RELAXED, __ATOMIC_RELAXED, __HIP_MEMORY_SCOPE_AGENT);
      }
      unsigned cap = 0;
      for (;;) {
        unsigned wv = __hip_atomic_load(&elect[8], __ATOMIC_RELAXED,
                                        __HIP_MEMORY_SCOPE_AGENT);
        if (wv != 0u) { if (wv == xcc + 1u) role = (int)t; break; }
        if (++cap > (1u << 22)) break;
        __builtin_amdgcn_s_sleep(2);
      }
    }
    sh_role = role;
  }
  __syncthreads();
  const int role = sh_role;
  if (role < 0) return;               // whole WG exits together

  const int w = tid >> 6, l = tid & 63;
  const int dir = w >> 1, p = w & 1;
  const int j0 = role * 32 + p * 16;
  const int lj = l & 15, lk = l >> 4;
  const float* whh = dir ? whhb : whhf;
  const float* bhh = dir ? bhhb : bhhf;
  volatile int* go_v = (volatile int*)&sh_go;

  // persistent W_hh fragments (A-operand)
  bf16x8 bfr[3][16];
#pragma unroll
  for (int g = 0; g < 3; ++g) {
    const float* wr = whh + (size_t)(g * 512 + j0 + lj) * 512;
#pragma unroll
    for (int kc = 0; kc < 16; ++kc) {
      const float* s4 = wr + kc * 32 + lk * 8;
      float4 a = *(const float4*)s4;
      float4 b = *(const float4*)(s4 + 4);
      bf16x8 v;
      v[0] = (short)f2bf(a.x); v[1] = (short)f2bf(a.y); v[2] = (short)f2bf(a.z); v[3] = (short)f2bf(a.w);
      v[4] = (short)f2bf(b.x); v[5] = (short)f2bf(b.y); v[6] = (short)f2bf(b.z); v[7] = (short)f2bf(b.w);
      bfr[g][kc] = v;
    }
  }
  f32x4 bbv[3];
#pragma unroll
  for (int g = 0; g < 3; ++g)
    bbv[g] = *(const f32x4*)&bhh[g * 512 + j0 + lk * 4];

  float hreg[2][4];
#pragma unroll
  for (int bt = 0; bt < 2; ++bt) {
    f32x4 hv = *(const f32x4*)&h0[((size_t)dir * 32 + bt * 16 + lj) * 512 + j0 + lk * 4];
#pragma unroll
    for (int r = 0; r < 4; ++r) hreg[bt][r] = hv[r];
  }

  // gi prefetch for step 0 (consumed in step 0's epilogue)
  uint2 guc[2][3];
  {
    const int tq0 = dir ? 511 : 0;
#pragma unroll
    for (int bt = 0; bt < 2; ++bt)
#pragma unroll
      for (int g = 0; g < 3; ++g)
        guc[bt][g] = *(const uint2*)(gi + ((size_t)tq0 * 32 + bt * 16 + lj) * 3072
                                     + dir * 1536 + g * 512 + j0 + lk * 4);
  }

  for (int s = 0; s < 512; ++s) {
    const int tq = dir ? (511 - s) : s;

    // ---- wait: all 16 WGs finished step s-1 (no gi loads outstanding:
    //      current step's gi is already in regs) ----
    if (s > 0) {
      if (w == 0) {
        const unsigned target = 4u * (unsigned)s;
        unsigned cap = 0;
        for (;;) {
          unsigned v = 0xFFFFFFFFu;
          if (l < 4) v = atom_rd_l2(cnt + (l << 5));
          if (__all((int)((l < 4) ? (v >= target) : 1))) break;
          if (++cap > (1u << 14)) break;   // terminates, never hangs
        }
        if (l == 0) *go_v = s;             // LDS broadcast to waves 1..3
      } else {
        unsigned cap = 0;
        while (*go_v < s) { if (++cap > (1u << 20)) break; }
      }
    }

    // stage h_prev of my dir into LDS: 2 waves/dir x 16 rows (L2-local reads)
    {
      const u16* src; int rstride, cbase;
      if (s == 0) { src = hinit + (size_t)dir * 32 * 512; rstride = 512; cbase = 0; }
      else { int tp = dir ? (tq + 1) : (tq - 1); src = y + (size_t)tp * 32 * 1024; rstride = 1024; cbase = dir * 512; }
#pragma unroll
      for (int r = 0; r < 16; ++r) {
        int row = p * 16 + r;
        gl_lds16<1>(src + (size_t)row * rstride + cbase + l * 8, &hl[dir][row * LSTR]);
      }
    }
    asm volatile("s_waitcnt vmcnt(0)" ::: "memory");
    __syncthreads();                      // staging visible to dir partner

    // prefetch NEXT step's gi now: covered by MFMA+epilogue (~1500cy),
    // retired by the epilogue-end vmcnt(0) at ~zero residual cost.
    uint2 gun[2][3];
    {
      const int sq = (s < 511) ? (s + 1) : 511;
      const int tqn = dir ? (511 - sq) : sq;
#pragma unroll
      for (int bt = 0; bt < 2; ++bt)
#pragma unroll
        for (int g = 0; g < 3; ++g)
          gun[bt][g] = *(const uint2*)(gi + ((size_t)tqn * 32 + bt * 16 + lj) * 3072
                                       + dir * 1536 + g * 512 + j0 + lk * 4);
    }

    f32x4 acc[2][3];
#pragma unroll
    for (int bt = 0; bt < 2; ++bt)
#pragma unroll
      for (int g = 0; g < 3; ++g)
        acc[bt][g] = bbv[g];

#pragma unroll
    for (int kc = 0; kc < 16; ++kc) {
      bf16x8 a0 = *(const bf16x8*)&hl[dir][lj * LSTR + kc * 32 + lk * 8];
      bf16x8 a1 = *(const bf16x8*)&hl[dir][(16 + lj) * LSTR + kc * 32 + lk * 8];
#pragma unroll
      for (int g = 0; g < 3; ++g) {        // swapped operands: D[row=j][col=b]
        acc[0][g] = __builtin_amdgcn_mfma_f32_16x16x32_bf16(bfr[g][kc], a0, acc[0][g], 0, 0, 0);
        acc[1][g] = __builtin_amdgcn_mfma_f32_16x16x32_bf16(bfr[g][kc], a1, acc[1][g], 0, 0, 0);
      }
    }

    // epilogue: gates + h update; one 8-B sc0 store per (lane, bt)
#pragma unroll
    for (int bt = 0; bt < 2; ++bt) {
      const int b = bt * 16 + lj;
      unsigned q[4];
      float hv[4];
#pragma unroll
      for (int r = 0; r < 4; ++r) {
        unsigned w0 = (r & 1) ? (((const unsigned*)&guc[bt][0])[r >> 1] >> 16)
                              : (((const unsigned*)&guc[bt][0])[r >> 1] & 0xffffu);
        unsigned w1 = (r & 1) ? (((const unsigned*)&guc[bt][1])[r >> 1] >> 16)
                              : (((const unsigned*)&guc[bt][1])[r >> 1] & 0xffffu);
        unsigned w2 = (r & 1) ? (((const unsigned*)&guc[bt][2])[r >> 1] >> 16)
                              : (((const unsigned*)&guc[bt][2])[r >> 1] & 0xffffu);
        float rr = frcp(1.f + __expf(-(bf2f(w0) + acc[bt][0][r])));
        float zz = frcp(1.f + __expf(-(bf2f(w1) + acc[bt][1][r])));
        float nx = bf2f(w2) + rr * acc[bt][2][r];
        float nn = 1.f - 2.f * frcp(1.f + __expf(2.f * nx));
        float h = (1.f - zz) * nn + zz * hreg[bt][r];
        hreg[bt][r] = h;
        hv[r] = h;
        q[r] = (unsigned)f2bf(h);
      }
      uint2 pack; pack.x = q[0] | (q[1] << 16); pack.y = q[2] | (q[3] << 16);
      st_u64_sc0(y + ((size_t)tq * 32 + b) * 1024 + dir * 512 + j0 + lk * 4, pack);
      if (s == 511) {
        float4 o; o.x = hv[0]; o.y = hv[1]; o.z = hv[2]; o.w = hv[3];
        *(float4*)&hn[((size_t)dir * 32 + b) * 512 + j0 + lk * 4] = o;
      }
    }

    // rotate gi double-buffer (register moves only)
#pragma unroll
    for (int bt = 0; bt < 2; ++bt)
#pragma unroll
      for (int g = 0; g < 3; ++g)
        guc[bt][g] = gun[bt][g];

    asm volatile("s_waitcnt vmcnt(0)" ::: "memory");  // y stores + gun retired
    __syncthreads();                      // all 4 waves drained
    if (tid == 0) atom_add_l2(cnt + ((role & 3) << 5), 1u);  // publish at L2
  }
}

// ---------------- host ----------------

extern "C" void kernel_launch(void* const* d_in, const int* in_sizes, int n_in,
                              void* d_out, int out_size, void* d_ws, size_t ws_size,
                              hipStream_t stream)
{
  const float* x     = (const float*)d_in[0];
  const float* h     = (const float*)d_in[1];
  const float* wih0f = (const float*)d_in[2];
  const float* whh0f = (const float*)d_in[3];
  const float* bih0f = (const float*)d_in[4];
  const float* bhh0f = (const float*)d_in[5];
  const float* wih0b = (const float*)d_in[6];
  const float* whh0b = (const float*)d_in[7];
  const float* bih0b = (const float*)d_in[8];
  const float* bhh0b = (const float*)d_in[9];
  const float* wih1f = (const float*)d_in[10];
  const float* whh1f = (const float*)d_in[11];
  const float* bih1f = (const float*)d_in[12];
  const float* bhh1f = (const float*)d_in[13];
  const float* wih1b = (const float*)d_in[14];
  const float* whh1b = (const float*)d_in[15];
  const float* bih1b = (const float*)d_in[16];
  const float* bhh1b = (const float*)d_in[17];
  const float* fcw   = (const float*)d_in[18];
  const float* fcb   = (const float*)d_in[19];
  (void)in_sizes; (void)n_in; (void)out_size;

  char* ws = (char*)d_ws;
  size_t off = 0;
  auto alloc = [&](size_t bytes) { void* p = ws + off; off += (bytes + 255) & ~(size_t)255; return p; };
  u16*      gi    = (u16*)     alloc(16384ull * 3072 * 2);   // 100.7 MB
  u16*      y0    = (u16*)     alloc(16384ull * 1024 * 2);   // 33.6 MB
  char*     y1r   = (char*)    alloc(16384ull * 1024 * 2);   // 33.6 MB (aliased below)
  u16*      Wfc   = (u16*)     alloc(512ull * 1024 * 2);
  u16*      hinit = (u16*)     alloc(4ull * 32 * 512 * 2);
  float*    bias0 = (float*)   alloc(3072 * 4);
  float*    bias1 = (float*)   alloc(3072 * 4);
  unsigned* sync  = (unsigned*)alloc(512 * 4);
  // layout (u32 idx): [0..127] cnt L0 (quads at 0/32/64/96); [128..255] cnt L1;
  //                   [256..264] elect L0; [384..392] elect L1
  size_t need = off;

  if (ws_size < need) {  // diagnosable failure instead of a page fault
    hipMemsetAsync(d_out, 0, (size_t)out_size * sizeof(float), stream);
    return;
  }

  // xb / Wih0 / Wih1 die after GEMM1; y1 written only after that -> alias.
  u16* y1   = (u16*)y1r;
  u16* xb   = (u16*)y1r;
  u16* Wih0 = (u16*)(y1r + 16777216);
  u16* Wih1 = (u16*)(y1r + 16777216 + 3145728);

  float* out = (float*)d_out;
  float* hn  = out + 512ull * 32 * 512;

  k_zero<<<2, 256, 0, stream>>>(sync, 512);
  auto cvt = [&](const float* s, u16* d, int n) {
    k_cvt<<<dim3((n / 4 + 255) / 256), 256, 0, stream>>>(s, d, n);
  };
  cvt(x, xb, 16384 * 512);
  cvt(wih0f, Wih0, 1536 * 512);
  cvt(wih0b, Wih0 + 1536 * 512, 1536 * 512);
  cvt(wih1f, Wih1, 1536 * 1024);
  cvt(wih1b, Wih1 + 1536 * 1024, 1536 * 1024);
  cvt(fcw, Wfc, 512 * 1024);
  cvt(h, hinit, 4 * 32 * 512);
  k_copyf<<<6, 256, 0, stream>>>(bih0f, bias0, 1536);
  k_copyf<<<6, 256, 0, stream>>>(bih0b, bias0 + 1536, 1536);
  k_copyf<<<6, 256, 0, stream>>>(bih1f, bias1, 1536);
  k_copyf<<<6, 256, 0, stream>>>(bih1b, bias1 + 1536, 1536);

  // layer 0
  k_gemm<true><<<dim3(128, 24), 256, 0, stream>>>(xb, Wih0, bias0, gi, 3072, 512);
  k_gru<<<128, 256, 0, stream>>>(gi, whh0f, whh0b, bhh0f, bhh0b,
                                 h, hinit, y0, hn, sync, sync + 256);
  // layer 1
  k_gemm<true><<<dim3(128, 24), 256, 0, stream>>>(y0, Wih1, bias1, gi, 3072, 1024);
  k_gru<<<128, 256, 0, stream>>>(gi, whh1f, whh1b, bhh1f, bhh1b,
                                 h + 2 * 32 * 512, hinit + 2 * 32 * 512,
                                 y1, hn + 2ull * 32 * 512, sync + 128, sync + 384);
  // FC
  k_gemm<false><<<dim3(128, 4), 256, 0, stream>>>(y1, Wfc, fcb, out, 512, 1024);
}